// Round 3
// baseline (144.686 us; speedup 1.0000x reference)
//
#include <hip/hip_runtime.h>
#include <cstdint>
#include <cstddef>

typedef unsigned short u16;
typedef __attribute__((ext_vector_type(8))) short short8;
typedef __attribute__((ext_vector_type(4))) float f32x4;

#define CIN   512
#define COUT  512
#define BATCH 16
#define HWSZ  1024      // 32*32
#define PADW  34        // 32 + 2 halo

static constexpr float MOD_SCALE  = 0.044194173824159216f;   // 1/sqrt(512)
static constexpr float CONV_SCALE = 0.014731391274719739f;   // 1/sqrt(512*9)

// workspace layout (bytes)
#define WS_S    0                              // 8192 f32   (32 KB)
#define WS_DSC  (32*1024)                      // 8192 f32   (32 KB)
#define WS_WSQ  (64*1024)                      // 262144 f32 (1 MB)
#define WS_WBT  (64*1024 + 1024*1024)          // 9*512*512 bf16 (4.5 MB)
#define WS_XSP  (WS_WBT + 9*512*512*2)         // 16*34*34*512 bf16 (~18 MB)

__device__ __forceinline__ u16 f2bf(float f) {
  union { float f; uint32_t u; } v; v.f = f;
  uint32_t r = v.u + 0x7fffu + ((v.u >> 16) & 1u);   // RNE
  return (u16)(r >> 16);
}

__device__ __forceinline__ void gload16(const void* g, void* l) {
  __builtin_amdgcn_global_load_lds(
      (const __attribute__((address_space(1))) void*)g,
      (__attribute__((address_space(3))) void*)l, 16, 0, 0);
}

// ---------------- s[b,i] = mod_scale * style[b,:] . mod_w[i,:] + mod_b[i] ----------------
__global__ void k_style(const float* __restrict__ style, const float* __restrict__ mod_w,
                        const float* __restrict__ mod_b, float* __restrict__ s_out) {
  int gid  = blockIdx.x * blockDim.x + threadIdx.x;
  int w    = gid >> 6, lane = gid & 63;
  int b    = w >> 9, i = w & 511;
  const float4* st = (const float4*)(style + (size_t)b * 512);
  const float4* mw = (const float4*)(mod_w + (size_t)i * 512);
  float4 a0 = st[lane * 2], a1 = st[lane * 2 + 1];
  float4 w0 = mw[lane * 2], w1 = mw[lane * 2 + 1];
  float acc = a0.x*w0.x + a0.y*w0.y + a0.z*w0.z + a0.w*w0.w
            + a1.x*w1.x + a1.y*w1.y + a1.z*w1.z + a1.w*w1.w;
  #pragma unroll
  for (int off = 32; off; off >>= 1) acc += __shfl_xor(acc, off);
  if (lane == 0) s_out[w] = acc * MOD_SCALE + mod_b[i];
}

// ---------------- fused: wsq[o,i] = sum_k w^2 ; wbT[kxy][o][i] = bf16(w) ----------------
__global__ void k_wprep(const float* __restrict__ w, float* __restrict__ wsq,
                        u16* __restrict__ wbt) {
  int idx = blockIdx.x * 256 + threadIdx.x;          // 262144 = o*512+i
  const float* p = w + (size_t)idx * 9;
  float a = 0.f;
  #pragma unroll
  for (int kxy = 0; kxy < 9; ++kxy) {
    float v = p[kxy];
    a += v * v;
    wbt[(size_t)kxy * 262144 + idx] = f2bf(v);
  }
  wsq[idx] = a;
}

// ---------------- dscale[b,o] = conv_scale * rsqrt(cs^2 * sum_i wsq[o,i]*s[b,i]^2 + 1e-8) ----
__global__ void k_dscale(const float* __restrict__ wsq, const float* __restrict__ s,
                         float* __restrict__ dsc) {
  int gid  = blockIdx.x * blockDim.x + threadIdx.x;
  int w    = gid >> 6, lane = gid & 63;
  int b    = w >> 9, o = w & 511;
  const float4* q4 = (const float4*)(wsq + (size_t)o * 512);
  const float4* s4 = (const float4*)(s   + (size_t)b * 512);
  float4 q0 = q4[lane * 2], q1 = q4[lane * 2 + 1];
  float4 t0 = s4[lane * 2], t1 = s4[lane * 2 + 1];
  float acc = q0.x*t0.x*t0.x + q0.y*t0.y*t0.y + q0.z*t0.z*t0.z + q0.w*t0.w*t0.w
            + q1.x*t1.x*t1.x + q1.y*t1.y*t1.y + q1.z*t1.z*t1.z + q1.w*t1.w*t1.w;
  #pragma unroll
  for (int off = 32; off; off >>= 1) acc += __shfl_xor(acc, off);
  if (lane == 0)
    dsc[w] = CONV_SCALE * rsqrtf(acc * CONV_SCALE * CONV_SCALE + 1e-8f);
}

// ---------------- xs_p[b][y+1][x+1][i] = bf16(x[b][i][y][x] * s[b][i])  (NCHW->NHWC) --------
__global__ void k_xs(const float* __restrict__ x, const float* __restrict__ s,
                     u16* __restrict__ xsp) {
  __shared__ float tile[64][33];
  int icb = blockIdx.x, y = blockIdx.y, b = blockIdx.z;
  int t = threadIdx.x;
  int i0 = icb * 64;
  int c  = t & 31;       // x coord
  int r0 = t >> 5;       // 0..7
  #pragma unroll
  for (int it = 0; it < 8; ++it) {
    int row = r0 + it * 8;                           // i_loc 0..63
    float sv = s[b * 512 + i0 + row];
    tile[row][c] = x[((size_t)(b * 512 + i0 + row)) * 1024 + y * 32 + c] * sv;
  }
  __syncthreads();
  int il = t & 63;
  int x0 = t >> 6;       // 0..3
  #pragma unroll
  for (int it = 0; it < 8; ++it) {
    int xc = x0 + it * 4;
    xsp[((size_t)((b * PADW + y + 1) * PADW) + (xc + 1)) * 512 + i0 + il] = f2bf(tile[il][xc]);
  }
}

// ---------------- implicit-GEMM conv + fused epilogue ----------------
// D[o][m] tile 128x128, K = 9*512 in steps of 64, 4 waves (2x2 of 64x64)
// T2: LDS XOR-swizzle (chunk ^= row&7), applied on global source + ds_read addr.
// T3-min: 2-phase double-buffer — issue next tile's global_load_lds BEFORE
// computing current tile; ONE __syncthreads (implicit vmcnt(0)) per K-step.
__global__ __launch_bounds__(256) void k_conv(
    const u16* __restrict__ wbt, const u16* __restrict__ xsp,
    const float* __restrict__ dsc, const float* __restrict__ noise,
    const float* __restrict__ nw, const float* __restrict__ abias,
    float* __restrict__ out)
{
  __shared__ u16 Ald[2][128 * 64];   // 32 KB (swizzled)
  __shared__ u16 Bld[2][128 * 64];   // 32 KB (swizzled)

  const int tid  = threadIdx.x;
  const int wave = tid >> 6, lane = tid & 63;
  const int o0 = blockIdx.x * 128;
  const int m0 = blockIdx.y * 128;
  const int b  = m0 >> 10;        // uniform per block (128 | 1024)

  // per-lane staging bases: lane covers row (base + lane>>3), 16-B chunk (lane&7).
  // swizzled source chunk = (lane&7) ^ (row&7) = (lane&7) ^ (lane>>3)
  const u16* gA[4]; const u16* gB[4]; u16* lA[4]; u16* lB[4];
  const int cc = (((lane & 7) ^ (lane >> 3)) * 8);
  #pragma unroll
  for (int q = 0; q < 4; ++q) {
    int r  = wave * 32 + q * 8 + (lane >> 3);
    gA[q] = wbt + (size_t)(o0 + r) * 512 + cc;
    int mg = m0 + r;
    int yy = (mg >> 5) & 31, xx = mg & 31;
    gB[q] = xsp + ((size_t)(b * PADW + yy) * PADW + xx) * 512 + cc;
    lA[q] = &Ald[0][(wave * 32 + q * 8) * 64];
    lB[q] = &Bld[0][(wave * 32 + q * 8) * 64];
  }

  f32x4 acc[4][4];
  #pragma unroll
  for (int i = 0; i < 4; ++i)
    #pragma unroll
    for (int j = 0; j < 4; ++j) acc[i][j] = (f32x4){0.f, 0.f, 0.f, 0.f};

  const int wo = (wave >> 1) * 64;   // o sub-block
  const int wm = (wave & 1) * 64;    // m sub-block
  const int lrow = lane & 15;
  const int lk   = (lane >> 4) * 8;
  const int rsw  = (lrow & 7) << 3;  // read-side swizzle (u16 units)

  // K-step -> global offsets
  auto offsets = [&](int ks, int& offA, int& offB) {
    int kxy = ks >> 3;
    int ib  = (ks & 7) << 6;
    int ky  = kxy / 3, kx = kxy - ky * 3;
    offA = kxy * 262144 + ib;
    offB = ((ky * PADW + kx) << 9) + ib;
  };

  // prologue: stage tile 0 into buf 0
  {
    int offA, offB;
    offsets(0, offA, offB);
    #pragma unroll
    for (int q = 0; q < 4; ++q) gload16(gA[q] + offA, lA[q]);
    #pragma unroll
    for (int q = 0; q < 4; ++q) gload16(gB[q] + offB, lB[q]);
  }
  __syncthreads();   // vmcnt(0) drain + barrier: buf0 ready

  for (int ks = 0; ks < 72; ++ks) {
    const int cur = ks & 1;
    const int curOff = cur * (128 * 64);

    // issue next tile's loads into the other buffer (overlaps with compute below)
    if (ks + 1 < 72) {
      int offA, offB;
      offsets(ks + 1, offA, offB);
      const int nxtOff = (cur ^ 1) * (128 * 64);
      #pragma unroll
      for (int q = 0; q < 4; ++q) gload16(gA[q] + offA, lA[q] + nxtOff);
      #pragma unroll
      for (int q = 0; q < 4; ++q) gload16(gB[q] + offB, lB[q] + nxtOff);
    }

    // compute current tile
    const u16* Ac = &Ald[0][curOff];
    const u16* Bc = &Bld[0][curOff];
    #pragma unroll
    for (int kh = 0; kh < 2; ++kh) {
      int kos = (kh * 32 + lk) ^ rsw;
      short8 av[4], bv[4];
      #pragma unroll
      for (int mi = 0; mi < 4; ++mi)
        av[mi] = *(const short8*)&Ac[(wo + mi * 16 + lrow) * 64 + kos];
      #pragma unroll
      for (int ni = 0; ni < 4; ++ni)
        bv[ni] = *(const short8*)&Bc[(wm + ni * 16 + lrow) * 64 + kos];
      #pragma unroll
      for (int mi = 0; mi < 4; ++mi)
        #pragma unroll
        for (int ni = 0; ni < 4; ++ni)
          acc[mi][ni] = __builtin_amdgcn_mfma_f32_16x16x32_bf16(
              av[mi], bv[ni], acc[mi][ni], 0, 0, 0);
    }

    // one barrier per K-step: drains vmcnt(0) (next tile landed) and
    // guarantees all waves finished reading buf[cur] before it's overwritten.
    __syncthreads();
  }

  // epilogue: demod*conv_scale, noise, bias, leaky(0.2)*sqrt(2)
  const float nwv = nw[0];
  const int mrow = (lane >> 4) << 2;
  #pragma unroll
  for (int mi = 0; mi < 4; ++mi) {
    #pragma unroll
    for (int ni = 0; ni < 4; ++ni) {
      int mg = m0 + wm + ni * 16 + lrow;
      int hw = mg & 1023;
      float nz = nwv * noise[b * 1024 + hw];
      #pragma unroll
      for (int r = 0; r < 4; ++r) {
        int og = o0 + wo + mi * 16 + mrow + r;
        float v = acc[mi][ni][r] * dsc[b * 512 + og] + nz + abias[og];
        v = (v > 0.f ? v : 0.2f * v) * 1.4142135623730951f;
        out[(size_t)(b * 512 + og) * 1024 + hw] = v;
      }
    }
  }
}

extern "C" void kernel_launch(void* const* d_in, const int* in_sizes, int n_in,
                              void* d_out, int out_size, void* d_ws, size_t ws_size,
                              hipStream_t stream) {
  const float* x      = (const float*)d_in[0];
  const float* style  = (const float*)d_in[1];
  const float* noise  = (const float*)d_in[2];
  const float* weight = (const float*)d_in[3];
  const float* mod_w  = (const float*)d_in[4];
  const float* mod_b  = (const float*)d_in[5];
  const float* nw     = (const float*)d_in[6];
  const float* abias  = (const float*)d_in[7];
  float* out = (float*)d_out;

  char* ws = (char*)d_ws;
  float* s_buf = (float*)(ws + WS_S);
  float* dsc   = (float*)(ws + WS_DSC);
  float* wsq   = (float*)(ws + WS_WSQ);
  u16*   wbt   = (u16*)(ws + WS_WBT);
  u16*   xsp   = (u16*)(ws + WS_XSP);

  // zero padded input (borders must be 0 every call; ws is not preserved)
  hipMemsetAsync(xsp, 0, (size_t)BATCH * PADW * PADW * 512 * 2, stream);

  k_style <<<2048, 256, 0, stream>>>(style, mod_w, mod_b, s_buf);
  k_wprep <<<1024, 256, 0, stream>>>(weight, wsq, wbt);
  k_dscale<<<2048, 256, 0, stream>>>(wsq, s_buf, dsc);
  k_xs    <<<dim3(8, 32, 16), 256, 0, stream>>>(x, s_buf, xsp);
  k_conv  <<<dim3(4, 128), 256, 0, stream>>>(wbt, xsp, dsc, noise, nw, abias, out);
}

// Round 4
// 114.707 us; speedup vs baseline: 1.2613x; 1.2613x over previous
//
#include <hip/hip_runtime.h>
#include <cstdint>
#include <cstddef>

typedef unsigned short u16;
typedef __attribute__((ext_vector_type(8))) short short8;
typedef __attribute__((ext_vector_type(4))) float f32x4;

#define CIN   512
#define COUT  512
#define BATCH 16
#define HWSZ  1024      // 32*32
#define PADW  34        // 32 + 2 halo

static constexpr float MOD_SCALE  = 0.044194173824159216f;   // 1/sqrt(512)
static constexpr float CONV_SCALE = 0.014731391274719739f;   // 1/sqrt(512*9)

// workspace layout (bytes)
#define WS_S    0                              // 8192 f32   (32 KB)
#define WS_DSC  (32*1024)                      // 8192 f32   (32 KB)
#define WS_WSQ  (64*1024)                      // 262144 f32 (1 MB)
#define WS_WBT  (64*1024 + 1024*1024)          // 9*512*512 bf16 (4.5 MB)
#define WS_XSP  (WS_WBT + 9*512*512*2)         // 16*34*34*512 bf16 (~18 MB)

__device__ __forceinline__ u16 f2bf(float f) {
  union { float f; uint32_t u; } v; v.f = f;
  uint32_t r = v.u + 0x7fffu + ((v.u >> 16) & 1u);   // RNE
  return (u16)(r >> 16);
}

__device__ __forceinline__ void gload16(const void* g, void* l) {
  __builtin_amdgcn_global_load_lds(
      (const __attribute__((address_space(1))) void*)g,
      (__attribute__((address_space(3))) void*)l, 16, 0, 0);
}

// ---------------- s[b,i] = mod_scale * style[b,:] . mod_w[i,:] + mod_b[i] ----------------
__global__ void k_style(const float* __restrict__ style, const float* __restrict__ mod_w,
                        const float* __restrict__ mod_b, float* __restrict__ s_out) {
  int gid  = blockIdx.x * blockDim.x + threadIdx.x;
  int w    = gid >> 6, lane = gid & 63;
  int b    = w >> 9, i = w & 511;
  const float4* st = (const float4*)(style + (size_t)b * 512);
  const float4* mw = (const float4*)(mod_w + (size_t)i * 512);
  float4 a0 = st[lane * 2], a1 = st[lane * 2 + 1];
  float4 w0 = mw[lane * 2], w1 = mw[lane * 2 + 1];
  float acc = a0.x*w0.x + a0.y*w0.y + a0.z*w0.z + a0.w*w0.w
            + a1.x*w1.x + a1.y*w1.y + a1.z*w1.z + a1.w*w1.w;
  #pragma unroll
  for (int off = 32; off; off >>= 1) acc += __shfl_xor(acc, off);
  if (lane == 0) s_out[w] = acc * MOD_SCALE + mod_b[i];
}

// ---------------- fused: wsq[o,i] = sum_k w^2 ; wbT[kxy][o][i] = bf16(w) ----------------
__global__ void k_wprep(const float* __restrict__ w, float* __restrict__ wsq,
                        u16* __restrict__ wbt) {
  int idx = blockIdx.x * 256 + threadIdx.x;          // 262144 = o*512+i
  const float* p = w + (size_t)idx * 9;
  float a = 0.f;
  #pragma unroll
  for (int kxy = 0; kxy < 9; ++kxy) {
    float v = p[kxy];
    a += v * v;
    wbt[(size_t)kxy * 262144 + idx] = f2bf(v);
  }
  wsq[idx] = a;
}

// ---------------- dscale[b,o] = conv_scale * rsqrt(cs^2 * sum_i wsq[o,i]*s[b,i]^2 + 1e-8) ----
__global__ void k_dscale(const float* __restrict__ wsq, const float* __restrict__ s,
                         float* __restrict__ dsc) {
  int gid  = blockIdx.x * blockDim.x + threadIdx.x;
  int w    = gid >> 6, lane = gid & 63;
  int b    = w >> 9, o = w & 511;
  const float4* q4 = (const float4*)(wsq + (size_t)o * 512);
  const float4* s4 = (const float4*)(s   + (size_t)b * 512);
  float4 q0 = q4[lane * 2], q1 = q4[lane * 2 + 1];
  float4 t0 = s4[lane * 2], t1 = s4[lane * 2 + 1];
  float acc = q0.x*t0.x*t0.x + q0.y*t0.y*t0.y + q0.z*t0.z*t0.z + q0.w*t0.w*t0.w
            + q1.x*t1.x*t1.x + q1.y*t1.y*t1.y + q1.z*t1.z*t1.z + q1.w*t1.w*t1.w;
  #pragma unroll
  for (int off = 32; off; off >>= 1) acc += __shfl_xor(acc, off);
  if (lane == 0)
    dsc[w] = CONV_SCALE * rsqrtf(acc * CONV_SCALE * CONV_SCALE + 1e-8f);
}

// ---------------- xs_p[b][y+1][x+1][i] = bf16(x[b][i][y][x] * s[b][i])  (NCHW->NHWC) --------
__global__ void k_xs(const float* __restrict__ x, const float* __restrict__ s,
                     u16* __restrict__ xsp) {
  __shared__ float tile[64][33];
  int icb = blockIdx.x, y = blockIdx.y, b = blockIdx.z;
  int t = threadIdx.x;
  int i0 = icb * 64;
  int c  = t & 31;       // x coord
  int r0 = t >> 5;       // 0..7
  #pragma unroll
  for (int it = 0; it < 8; ++it) {
    int row = r0 + it * 8;                           // i_loc 0..63
    float sv = s[b * 512 + i0 + row];
    tile[row][c] = x[((size_t)(b * 512 + i0 + row)) * 1024 + y * 32 + c] * sv;
  }
  __syncthreads();
  int il = t & 63;
  int x0 = t >> 6;       // 0..3
  #pragma unroll
  for (int it = 0; it < 8; ++it) {
    int xc = x0 + it * 4;
    xsp[((size_t)((b * PADW + y + 1) * PADW) + (xc + 1)) * 512 + i0 + il] = f2bf(tile[il][xc]);
  }
}

// ---------------- implicit-GEMM conv + fused epilogue ----------------
// Tile 256(o) x 128(m), 8 waves (4o x 2m, per-wave 64x64), K=4608 in 72 steps of 64.
// Tri-buffered LDS, counted vmcnt(6) pipeline (T4): one raw s_barrier per K-step,
// stage(ks+2) issued right after the barrier, overlapping compute(ks).
// T2: LDS XOR-swizzle (chunk ^= row&7) via pre-swizzled global source + swizzled ds_read.
// T1: XCD-aware block swizzle (grid 256 = 8 XCD x 32): same-o blocks share one XCD's L2.
__global__ __launch_bounds__(512, 2) void k_conv(
    const u16* __restrict__ wbt, const u16* __restrict__ xsp,
    const float* __restrict__ dsc, const float* __restrict__ noise,
    const float* __restrict__ nw, const float* __restrict__ abias,
    float* __restrict__ out)
{
  __shared__ u16 Ald[3 * 16384];   // 3 x 256x64 bf16 = 96 KB (swizzled)
  __shared__ u16 Bld[3 * 8192];    // 3 x 128x64 bf16 = 48 KB (swizzled)

  const int tid  = threadIdx.x;
  const int wave = tid >> 6, lane = tid & 63;

  // T1: XCD swizzle. 256 blocks round-robin XCDs by bid&7; give each XCD 32
  // consecutive logical tiles (same o-slice -> weights L2-resident per XCD).
  const int bid = blockIdx.x;
  const int swz = (bid & 7) * 32 + (bid >> 3);
  const int o0 = (swz >> 7) << 8;     // 0 or 256
  const int m0 = (swz & 127) << 7;    // 0..16256
  const int b  = m0 >> 10;            // uniform per block

  // staging bases: lane covers row (base + lane>>3), 16-B chunk (lane&7);
  // swizzled source chunk = (lane&7) ^ (row&7)
  const int cc = (((lane & 7) ^ (lane >> 3)) * 8);
  const u16* gA[4]; int lAo[4];
  #pragma unroll
  for (int q = 0; q < 4; ++q) {
    int r = wave * 32 + q * 8 + (lane >> 3);          // 0..255
    gA[q] = wbt + (size_t)(o0 + r) * 512 + cc;
    lAo[q] = (wave * 32 + q * 8) * 64;
  }
  const u16* gB[2]; int lBo[2];
  #pragma unroll
  for (int q = 0; q < 2; ++q) {
    int r = wave * 16 + q * 8 + (lane >> 3);          // 0..127
    int mg = m0 + r;
    int yy = (mg >> 5) & 31, xx = mg & 31;
    gB[q] = xsp + ((size_t)(b * PADW + yy) * PADW + xx) * 512 + cc;
    lBo[q] = (wave * 16 + q * 8) * 64;
  }

  f32x4 acc[4][4];
  #pragma unroll
  for (int i = 0; i < 4; ++i)
    #pragma unroll
    for (int j = 0; j < 4; ++j) acc[i][j] = (f32x4){0.f, 0.f, 0.f, 0.f};

  const int wo = (wave >> 1) * 64;   // o sub-block: 0/64/128/192
  const int wm = (wave & 1) * 64;    // m sub-block: 0/64
  const int lrow = lane & 15;
  const int lk   = (lane >> 4) * 8;
  const int rsw  = (lrow & 7) << 3;  // read-side swizzle (u16 units)

  // issue the 6 global_load_lds for K-step ks into buffers at (sa, sb)
  auto stage = [&](int ks, int sa, int sb) {
    int kxy = ks >> 3, ib = (ks & 7) << 6;
    int ky = kxy / 3, kx = kxy - ky * 3;
    int offA = kxy * 262144 + ib;
    int offB = ((ky * PADW + kx) << 9) + ib;
    #pragma unroll
    for (int q = 0; q < 4; ++q) gload16(gA[q] + offA, &Ald[sa + lAo[q]]);
    #pragma unroll
    for (int q = 0; q < 2; ++q) gload16(gB[q] + offB, &Bld[sb + lBo[q]]);
  };

  auto compute = [&](int ca, int cb) {
    #pragma unroll
    for (int kh = 0; kh < 2; ++kh) {
      int kos = (kh * 32 + lk) ^ rsw;
      short8 av[4], bv[4];
      #pragma unroll
      for (int mi = 0; mi < 4; ++mi)
        av[mi] = *(const short8*)&Ald[ca + (wo + mi * 16 + lrow) * 64 + kos];
      #pragma unroll
      for (int ni = 0; ni < 4; ++ni)
        bv[ni] = *(const short8*)&Bld[cb + (wm + ni * 16 + lrow) * 64 + kos];
      #pragma unroll
      for (int mi = 0; mi < 4; ++mi)
        #pragma unroll
        for (int ni = 0; ni < 4; ++ni)
          acc[mi][ni] = __builtin_amdgcn_mfma_f32_16x16x32_bf16(
              av[mi], bv[ni], acc[mi][ni], 0, 0, 0);
    }
  };

  // prologue: 12 loads in flight (stage 0 -> buf0, stage 1 -> buf1)
  stage(0, 0, 0);
  stage(1, 16384, 8192);

  // 72 K-steps = 24 x 3 (compile-time buffer rotation).
  // Per step ks: wait own stage(ks) landed (vmcnt(6): stage(ks+1) stays in
  // flight), barrier, issue stage(ks+2) into buf[(ks+2)%3], compute buf[ks%3].
  for (int t = 0; t < 24; ++t) {
    int k0 = t * 3;
    // ks = k0 (buf0), stage -> buf2
    asm volatile("s_waitcnt vmcnt(6)" ::: "memory");
    __builtin_amdgcn_s_barrier();
    if (k0 + 2 < 72) stage(k0 + 2, 32768, 16384);
    compute(0, 0);
    // ks = k0+1 (buf1), stage -> buf0
    asm volatile("s_waitcnt vmcnt(6)" ::: "memory");
    __builtin_amdgcn_s_barrier();
    if (k0 + 3 < 72) stage(k0 + 3, 0, 0);
    compute(16384, 8192);
    // ks = k0+2 (buf2), stage -> buf1
    if (k0 + 2 == 71) { asm volatile("s_waitcnt vmcnt(0)" ::: "memory"); }
    else              { asm volatile("s_waitcnt vmcnt(6)" ::: "memory"); }
    __builtin_amdgcn_s_barrier();
    if (k0 + 4 < 72) stage(k0 + 4, 16384, 8192);
    compute(32768, 16384);
  }

  // epilogue: demod*conv_scale, noise, bias, leaky(0.2)*sqrt(2)
  const float nwv = nw[0];
  const int mrow = (lane >> 4) << 2;
  #pragma unroll
  for (int mi = 0; mi < 4; ++mi) {
    #pragma unroll
    for (int ni = 0; ni < 4; ++ni) {
      int mg = m0 + wm + ni * 16 + lrow;
      int hw = mg & 1023;
      float nz = nwv * noise[b * 1024 + hw];
      #pragma unroll
      for (int r = 0; r < 4; ++r) {
        int og = o0 + wo + mi * 16 + mrow + r;
        float v = acc[mi][ni][r] * dsc[b * 512 + og] + nz + abias[og];
        v = (v > 0.f ? v : 0.2f * v) * 1.4142135623730951f;
        out[(size_t)(b * 512 + og) * 1024 + hw] = v;
      }
    }
  }
}

extern "C" void kernel_launch(void* const* d_in, const int* in_sizes, int n_in,
                              void* d_out, int out_size, void* d_ws, size_t ws_size,
                              hipStream_t stream) {
  const float* x      = (const float*)d_in[0];
  const float* style  = (const float*)d_in[1];
  const float* noise  = (const float*)d_in[2];
  const float* weight = (const float*)d_in[3];
  const float* mod_w  = (const float*)d_in[4];
  const float* mod_b  = (const float*)d_in[5];
  const float* nw     = (const float*)d_in[6];
  const float* abias  = (const float*)d_in[7];
  float* out = (float*)d_out;

  char* ws = (char*)d_ws;
  float* s_buf = (float*)(ws + WS_S);
  float* dsc   = (float*)(ws + WS_DSC);
  float* wsq   = (float*)(ws + WS_WSQ);
  u16*   wbt   = (u16*)(ws + WS_WBT);
  u16*   xsp   = (u16*)(ws + WS_XSP);

  // zero padded input (borders must be 0 every call; ws is not preserved)
  hipMemsetAsync(xsp, 0, (size_t)BATCH * PADW * PADW * 512 * 2, stream);

  k_style <<<2048, 256, 0, stream>>>(style, mod_w, mod_b, s_buf);
  k_wprep <<<1024, 256, 0, stream>>>(weight, wsq, wbt);
  k_dscale<<<2048, 256, 0, stream>>>(wsq, s_buf, dsc);
  k_xs    <<<dim3(8, 32, 16), 256, 0, stream>>>(x, s_buf, xsp);
  k_conv  <<<256, 512, 0, stream>>>(wbt, xsp, dsc, noise, nw, abias, out);
}